// Round 2
// baseline (182.540 us; speedup 1.0000x reference)
//
#include <hip/hip_runtime.h>
#include <stdint.h>

// TripletRankingLoss, bit-exact JAX threefry (partitionable) replication.
// R13: inline-asm 4-stream threefry. R12's C++-level interleave (tf_bits4) was
// RE-SERIALIZED by LLVM's pressure-greedy scheduler (VGPR_Count=24 proves <4
// live streams; dur unchanged 127us). Counter check: VALUBusy 80% == 61K
// wave-instrs/SIMD x 4-cyc LEGACY accounting / (127us x 2.4GHz) exactly ->
// gfx94x formula fallback double-counts; TRUE issue occupancy ~40%, kernel is
// latency-stalled on the serial add->rotl->xor chain. Fix the scheduler can't
// undo: one asm volatile block computing all 4 streams round-interleaved
// (dep distance >=4 instrs = >=8 issue cycles). Keys in SGPRs (1 SGPR read
// per VALU instr - legal), rotates = v_alignbit_b32 with inline-const shift.
// Loads/compares/tail/sort_kernel byte-identical to R11/R12 (bit-exact).
// Intra-kernel spin-sync BANNED (R10: cache-storm, 3.4x regression);
// unroll-8 BANNED (R5-R7 poison).

#define B 8192
#define K 1024

struct TFOut { uint32_t a, b; };

__host__ __device__ constexpr uint32_t rotl32(uint32_t x, int r) {
    return (x << r) | (x >> (32 - r));
}

// Full Threefry-2x32 (20 rounds), exactly as jax/_src/prng.py — compile-time
// only, to derive the split keys.
__host__ __device__ constexpr TFOut threefry_full(uint32_t k0, uint32_t k1,
                                                  uint32_t x0, uint32_t x1) {
    const uint32_t ks2 = k0 ^ k1 ^ 0x1BD11BDAu;
    x0 += k0; x1 += k1;
    x0 += x1; x1 = rotl32(x1,13); x1 ^= x0;
    x0 += x1; x1 = rotl32(x1,15); x1 ^= x0;
    x0 += x1; x1 = rotl32(x1,26); x1 ^= x0;
    x0 += x1; x1 = rotl32(x1,6);  x1 ^= x0;
    x0 += k1; x1 += ks2 + 1u;
    x0 += x1; x1 = rotl32(x1,17); x1 ^= x0;
    x0 += x1; x1 = rotl32(x1,29); x1 ^= x0;
    x0 += x1; x1 = rotl32(x1,16); x1 ^= x0;
    x0 += x1; x1 = rotl32(x1,24); x1 ^= x0;
    x0 += ks2; x1 += k0 + 2u;
    x0 += x1; x1 = rotl32(x1,13); x1 ^= x0;
    x0 += x1; x1 = rotl32(x1,15); x1 ^= x0;
    x0 += x1; x1 = rotl32(x1,26); x1 ^= x0;
    x0 += x1; x1 = rotl32(x1,6);  x1 ^= x0;
    x0 += k0; x1 += k1 + 3u;
    x0 += x1; x1 = rotl32(x1,17); x1 ^= x0;
    x0 += x1; x1 = rotl32(x1,29); x1 ^= x0;
    x0 += x1; x1 = rotl32(x1,16); x1 ^= x0;
    x0 += x1; x1 = rotl32(x1,24); x1 ^= x0;
    x0 += k1; x1 += ks2 + 4u;
    x0 += x1; x1 = rotl32(x1,13); x1 ^= x0;
    x0 += x1; x1 = rotl32(x1,15); x1 ^= x0;
    x0 += x1; x1 = rotl32(x1,26); x1 ^= x0;
    x0 += x1; x1 = rotl32(x1,6);  x1 ^= x0;
    x0 += ks2; x1 += k0 + 5u;
    return TFOut{x0, x1};
}

// jax.random.key(42) -> (0,42); partitionable split: kp=block(0,0), kn=block(0,1).
constexpr TFOut KP = threefry_full(0u, 42u, 0u, 0u);
constexpr TFOut KN = threefry_full(0u, 42u, 0u, 1u);

// Scalar device threefry (tail loop + boundary zone only).
template<uint32_t TK0, uint32_t TK1>
__device__ __forceinline__ uint32_t tf_bits(uint32_t x1) {
    constexpr uint32_t KS2 = TK0 ^ TK1 ^ 0x1BD11BDAu;
    uint32_t x0 = TK0;
#define RND(r) x0 += x1; x1 = __builtin_amdgcn_alignbit(x1, x1, 32 - (r)); x1 ^= x0;
    RND(13) RND(15) RND(26) RND(6)
    x0 += TK1; x1 += KS2 + 1u;
    RND(17) RND(29) RND(16) RND(24)
    x0 += KS2; x1 += TK0 + 2u;
    RND(13) RND(15) RND(26) RND(6)
    x0 += TK0; x1 += TK1 + 3u;
    RND(17) RND(29) RND(16) RND(24)
    x0 += TK1; x1 += KS2 + 4u;
    RND(13) RND(15) RND(26) RND(6)
    x0 += KS2; x1 += TK0 + 5u;
#undef RND
    return x0 ^ x1;
}

// ---- 4-stream interleaved threefry, pinned schedule (inline asm) ----------
// %0-%3 = x1 of streams a..d (in: pre-keyed counter j+kb; out: x0^x1).
// %4-%7 = x0 scratch. %8-%15 = key-schedule constants in SGPRs.
// Round: x0+=x1 ; x1=rotl(x1,r)=alignbit(x1,x1,32-r) ; x1^=x0.
// Grouped 4-wide per op class -> dependent instrs >=4 slots (>=8 cyc) apart.
#define TF4R(S) \
    "v_add_u32 %4, %4, %0\n\t" \
    "v_add_u32 %5, %5, %1\n\t" \
    "v_add_u32 %6, %6, %2\n\t" \
    "v_add_u32 %7, %7, %3\n\t" \
    "v_alignbit_b32 %0, %0, %0, " S "\n\t" \
    "v_alignbit_b32 %1, %1, %1, " S "\n\t" \
    "v_alignbit_b32 %2, %2, %2, " S "\n\t" \
    "v_alignbit_b32 %3, %3, %3, " S "\n\t" \
    "v_xor_b32 %0, %0, %4\n\t" \
    "v_xor_b32 %1, %1, %5\n\t" \
    "v_xor_b32 %2, %2, %6\n\t" \
    "v_xor_b32 %3, %3, %7\n\t"

#define TF4I(KA, KB) \
    "v_add_u32 %4, " KA ", %4\n\t" \
    "v_add_u32 %5, " KA ", %5\n\t" \
    "v_add_u32 %6, " KA ", %6\n\t" \
    "v_add_u32 %7, " KA ", %7\n\t" \
    "v_add_u32 %0, " KB ", %0\n\t" \
    "v_add_u32 %1, " KB ", %1\n\t" \
    "v_add_u32 %2, " KB ", %2\n\t" \
    "v_add_u32 %3, " KB ", %3\n\t"

// rotl r -> alignbit shift (32-r): 13->19, 15->17, 26->6, 6->26,
//                                  17->15, 29->3, 16->16, 24->8.
template<uint32_t TK0, uint32_t TK1>
__device__ __forceinline__ void tf_bits4_asm(uint32_t& A, uint32_t& Bv,
                                             uint32_t& C, uint32_t& D) {
    constexpr uint32_t KS2 = TK0 ^ TK1 ^ 0x1BD11BDAu;
    uint32_t t0, t1, t2, t3;
    asm volatile(
        "v_mov_b32 %4, %12\n\t"          // x0 = TK0 (all 4 streams)
        "v_mov_b32 %5, %12\n\t"
        "v_mov_b32 %6, %12\n\t"
        "v_mov_b32 %7, %12\n\t"
        TF4R("19") TF4R("17") TF4R("6") TF4R("26")
        TF4I("%8", "%9")                 // x0+=TK1,  x1+=KS2+1
        TF4R("15") TF4R("3") TF4R("16") TF4R("8")
        TF4I("%10", "%11")               // x0+=KS2,  x1+=TK0+2
        TF4R("19") TF4R("17") TF4R("6") TF4R("26")
        TF4I("%12", "%13")               // x0+=TK0,  x1+=TK1+3
        TF4R("15") TF4R("3") TF4R("16") TF4R("8")
        TF4I("%8", "%14")                // x0+=TK1,  x1+=KS2+4
        TF4R("19") TF4R("17") TF4R("6") TF4R("26")
        TF4I("%10", "%15")               // x0+=KS2,  x1+=TK0+5
        "v_xor_b32 %0, %0, %4\n\t"       // out = x0 ^ x1
        "v_xor_b32 %1, %1, %5\n\t"
        "v_xor_b32 %2, %2, %6\n\t"
        "v_xor_b32 %3, %3, %7"
        : "+v"(A), "+v"(Bv), "+v"(C), "+v"(D),
          "=&v"(t0), "=&v"(t1), "=&v"(t2), "=&v"(t3)
        : "s"(TK1), "s"(KS2 + 1u), "s"(KS2), "s"(TK0 + 2u),
          "s"(TK0), "s"(TK1 + 3u), "s"(KS2 + 4u), "s"(TK0 + 5u));
}

__device__ __forceinline__ void mrg(uint32_t& H, uint32_t& J, uint32_t h2, uint32_t j2) {
    if (h2 > H || (h2 == H && j2 < J)) { H = h2; J = j2; }  // j tie: smaller wins
}

// Unchecked-zone scan: every element passes the predicate by construction.
// Unroll-4, preload next group (over-read past `end` stays inside d_ws).
// Slot assignment and stream order identical to R11/R12 (tie behavior kept).
template<uint32_t TK0, uint32_t TK1>
__device__ __forceinline__ void scan_main(const uint16_t* __restrict__ idx,
                                          int beg, int end, int lane,
                                          uint32_t kb, uint32_t& H, uint32_t& J)
{
    uint32_t h0 = 0, h1 = 0, h2 = 0, h3 = 0;
    uint32_t j0 = 0xFFFFFFFFu, j1 = 0xFFFFFFFFu, j2 = 0xFFFFFFFFu, j3 = 0xFFFFFFFFu;
    int s = beg;
    uint32_t a = 0, b = 0, c = 0, d = 0;
    if (s + 256 <= end) {
        a = idx[s + lane];       b = idx[s + lane + 64];
        c = idx[s + lane + 128]; d = idx[s + lane + 192];
    }
    while (s + 256 <= end) {
        const int sn = s + 256;
        const uint32_t na = idx[sn + lane];        // in flight across the 4 hashes
        const uint32_t nb = idx[sn + lane + 64];
        const uint32_t nc = idx[sn + lane + 128];
        const uint32_t nd = idx[sn + lane + 192];
        uint32_t ha = a + kb, hb = b + kb, hc = c + kb, hd = d + kb;
        tf_bits4_asm<TK0, TK1>(ha, hb, hc, hd);
        ha >>= 9; hb >>= 9; hc >>= 9; hd >>= 9;
        if (ha > h0) { h0 = ha; j0 = a; }
        if (hb > h1) { h1 = hb; j1 = b; }
        if (hc > h2) { h2 = hc; j2 = c; }
        if (hd > h3) { h3 = hd; j3 = d; }
        a = na; b = nb; c = nc; d = nd;
        s = sn;
    }
    for (int t = s + lane; t < end; t += 64) {
        const uint32_t j = idx[t];
        const uint32_t hh = tf_bits<TK0, TK1>(j + kb) >> 9;
        if (hh > h0) { h0 = hh; j0 = j; }
    }
    mrg(h0, j0, h1, j1); mrg(h2, j2, h3, j3); mrg(h0, j0, h2, j2);
    mrg(H, J, h0, j0);
}

// Boundary zone (~16 elems/row): exact fp32 predicate per element.
template<uint32_t TK0, uint32_t TK1, bool NEG>
__device__ __forceinline__ void scan_bnd(const float* __restrict__ st,
                                         const uint16_t* __restrict__ idx,
                                         int beg, int end, int lane, float ti,
                                         uint32_t kb, uint32_t& H, uint32_t& J,
                                         bool& found)
{
    for (int t = beg + lane; t < end; t += 64) {
        const float tj = st[t];
        const uint32_t j = idx[t];
        const uint32_t hh = tf_bits<TK0, TK1>(j + kb) >> 9;
        const float dd = ti - tj;
        const bool ok = NEG ? (dd > 0.1f) : (dd < -0.1f);
        if (ok) {
            found = true;
            if (hh > H || (hh == H && j < J)) { H = hh; J = j; }
        }
    }
}

// ------------- Kernel A: LDS-staged counting sort + accumulator init --------
// Single block, 1024 threads. Scatter lands in LDS (fast), then dumps to
// global fully coalesced (float4 / uint4).  (byte-identical to R11/R12)
__global__ __launch_bounds__(1024) void sort_kernel(
    const float* __restrict__ targets,
    float* __restrict__ sorted_t, uint16_t* __restrict__ sorted_idx,
    int* __restrict__ bin_start, float* __restrict__ loss_sum,
    float* __restrict__ valid_sum, unsigned int* __restrict__ done)
{
    __shared__ int hist[K];                       //  4 KB
    __shared__ int cursor[K];                     //  4 KB
    __shared__ int wsum[16];
    __shared__ float st_lds[B];                   // 32 KB
    __shared__ __align__(16) uint16_t si_lds[B];  // 16 KB   (total ~56 KB)
    const int tid = threadIdx.x;

    hist[tid] = 0;
    if (tid == 0) { *loss_sum = 0.0f; *valid_sum = 0.0f; *done = 0u; }
    __syncthreads();

    // Load 8 elements/thread as 2x float4 (coalesced).
    const float4* t4 = reinterpret_cast<const float4*>(targets);
    const float4 va = t4[tid];
    const float4 vb = t4[tid + 1024];
    float v[8] = {va.x, va.y, va.z, va.w, vb.x, vb.y, vb.z, vb.w};
    int   bn[8];
#pragma unroll
    for (int i = 0; i < 8; ++i) {
        int b = (int)(v[i] * (float)K);
        b = b < 0 ? 0 : (b > K - 1 ? K - 1 : b);
        bn[i] = b;
        atomicAdd(&hist[b], 1);
    }
    __syncthreads();

    // shfl-based inclusive scan over 1024 bins (1 bin/thread) — proven R8 code.
    const int cnt  = hist[tid];
    const int lane = tid & 63;
    const int wv   = tid >> 6;
    int incl = cnt;
    for (int d = 1; d < 64; d <<= 1) {
        const int o = __shfl_up(incl, d, 64);
        if (lane >= d) incl += o;
    }
    if (lane == 63) wsum[wv] = incl;
    __syncthreads();
    if (tid < 16) {
        int wincl = wsum[tid];
        for (int d = 1; d < 16; d <<= 1) {
            const int o = __shfl_up(wincl, d, 64);
            if (tid >= d) wincl += o;
        }
        wsum[tid] = wincl;
    }
    __syncthreads();
    incl += (wv > 0) ? wsum[wv - 1] : 0;
    bin_start[tid + 1] = incl;
    if (tid == 0) bin_start[0] = 0;
    cursor[tid] = incl - cnt;
    __syncthreads();

    // Scatter into LDS staging (element e for v[i]: i<4 -> 4*tid+i, else 4096+4*tid+i-4).
#pragma unroll
    for (int i = 0; i < 8; ++i) {
        const int e = (i < 4) ? (4 * tid + i) : (4096 + 4 * tid + (i - 4));
        const int p = atomicAdd(&cursor[bn[i]], 1);
        st_lds[p] = v[i];
        si_lds[p] = (uint16_t)e;
    }
    __syncthreads();

    // Coalesced dump to global.
    reinterpret_cast<float4*>(sorted_t)[tid]        = reinterpret_cast<float4*>(st_lds)[tid];
    reinterpret_cast<float4*>(sorted_t)[tid + 1024] = reinterpret_cast<float4*>(st_lds)[tid + 1024];
    reinterpret_cast<uint4*>(sorted_idx)[tid]       = reinterpret_cast<uint4*>(si_lds)[tid];
}

// ------------- Kernel B: per-wave row scan + fused finalize -----------------
// Structure identical to R8/R9/R11/R12; the 4-hash computation is now a
// pinned-schedule asm block. launch_bounds(256,8): 64-VGPR budget.
__global__ __launch_bounds__(256, 8) void rows_kernel(
    const float* __restrict__ preds, const float* __restrict__ targets,
    const float* __restrict__ sorted_t, const uint16_t* __restrict__ sorted_idx,
    const int* __restrict__ bin_start,
    float* __restrict__ loss_sum, float* __restrict__ valid_sum,
    unsigned int* __restrict__ done, float* __restrict__ out)
{
    __shared__ float sl[4], sv[4];
    const int lane = threadIdx.x & 63;
    const int wv   = threadIdx.x >> 6;
    const int row  = (blockIdx.x << 2) + wv;

    const float ti = targets[row];
    const uint32_t base = (uint32_t)row << 13;   // row * B

    // Candidate ranges from bins (1e-4 conservative margin >> fp32 ulp slack;
    // boundary zone gets the exact fp32 predicate).
    const float cutn = ti - 0.1f;
    int bl = (int)floorf((cutn - 1e-4f) * (float)K);
    int bh = (int)floorf((cutn + 1e-4f) * (float)K) + 1;
    bl = bl < 0 ? 0 : (bl > K ? K : bl);
    bh = bh < 0 ? 0 : (bh > K ? K : bh);
    const int un_end = bin_start[bl];   // unchecked neg: [0, un_end)
    const int cn_end = bin_start[bh];   // checked  neg: [un_end, cn_end)

    const float cutp = ti + 0.1f;
    int pl = (int)floorf((cutp - 1e-4f) * (float)K);
    int ph = (int)floorf((cutp + 1e-4f) * (float)K) + 1;
    pl = pl < 0 ? 0 : (pl > K ? K : pl);
    ph = ph < 0 ? 0 : (ph > K ? K : ph);
    const int cp_beg = bin_start[pl];   // checked  pos: [cp_beg, up_beg)
    const int up_beg = bin_start[ph];   // unchecked pos: [up_beg, B)

    uint32_t Hn = 0, Jn = 0xFFFFFFFFu;
    bool fn = false;
    scan_main<KN.a, KN.b>(sorted_idx, 0, un_end, lane, base + KN.b, Hn, Jn);
    scan_bnd<KN.a, KN.b, true>(sorted_t, sorted_idx, un_end, cn_end, lane, ti,
                               base + KN.b, Hn, Jn, fn);
    const bool valid_n = (un_end > 0) || __any(fn);

    uint32_t Hp = 0, Jp = 0xFFFFFFFFu;
    bool fp2 = false;
    scan_main<KP.a, KP.b>(sorted_idx, up_beg, B, lane, base + KP.b, Hp, Jp);
    scan_bnd<KP.a, KP.b, false>(sorted_t, sorted_idx, cp_beg, up_beg, lane, ti,
                                base + KP.b, Hp, Jp, fp2);
    const bool valid_p = (up_beg < B) || __any(fp2);

    // In-wave (h, j) max-reduction with first-index tie-break.
    for (int off = 32; off > 0; off >>= 1) {
        const uint32_t ohn = __shfl_down(Hn, off, 64);
        const uint32_t ojn = __shfl_down(Jn, off, 64);
        if (ohn > Hn || (ohn == Hn && ojn < Jn)) { Hn = ohn; Jn = ojn; }
        const uint32_t ohp = __shfl_down(Hp, off, 64);
        const uint32_t ojp = __shfl_down(Jp, off, 64);
        if (ohp > Hp || (ohp == Hp && ojp < Jp)) { Hp = ohp; Jp = ojp; }
    }

    if (lane == 0) {
        float loss = 0.0f, valid = 0.0f;
        if (valid_n && valid_p) {
            const float per = 0.5f - (preds[Jp & 8191u] - preds[Jn & 8191u]);
            loss = per > 0.0f ? per : 0.0f;
            valid = 1.0f;
        }
        sl[wv] = loss; sv[wv] = valid;
    }
    __syncthreads();
    if (threadIdx.x == 0) {
        atomicAdd(loss_sum,  sl[0] + sl[1] + sl[2] + sl[3]);
        atomicAdd(valid_sum, sv[0] + sv[1] + sv[2] + sv[3]);
        __threadfence();
        const unsigned int old = atomicAdd(done, 1u);
        if (old == gridDim.x - 1u) {          // last block finalizes
            const float ls = atomicAdd(loss_sum, 0.0f);
            const float vs = atomicAdd(valid_sum, 0.0f);
            out[0] = vs > 0.0f ? ls / fmaxf(vs, 1.0f) : 0.0f;
        }
    }
}

extern "C" void kernel_launch(void* const* d_in, const int* in_sizes, int n_in,
                              void* d_out, int out_size, void* d_ws, size_t ws_size,
                              hipStream_t stream) {
    const float* preds   = (const float*)d_in[0];
    const float* targets = (const float*)d_in[1];

    // Layout identical to R4/R8 (proven): watermark ~57.4 KB. The 256 words
    // (512 u16 entries) after sorted_idx are the unroll-4 over-read slack.
    float* ws = (float*)d_ws;
    float*        sorted_t   = ws;                       // B floats
    uint16_t*     sorted_idx = (uint16_t*)(ws + B);      // B u16 + slack
    int*          bin_start  = (int*)(ws + B + B / 2 + 256); // K+1 ints
    float*        loss_sum   = ws + B + B / 2 + 2048;
    float*        valid_sum  = loss_sum + 1;
    unsigned int* done       = (unsigned int*)(loss_sum + 2);

    sort_kernel<<<1, 1024, 0, stream>>>(targets, sorted_t, sorted_idx, bin_start,
                                        loss_sum, valid_sum, done);
    rows_kernel<<<B / 4, 256, 0, stream>>>(preds, targets, sorted_t, sorted_idx,
                                           bin_start, loss_sum, valid_sum, done,
                                           (float*)d_out);
}

// Round 3
// 178.304 us; speedup vs baseline: 1.0238x; 1.0238x over previous
//
#include <hip/hip_runtime.h>
#include <stdint.h>

// TripletRankingLoss, bit-exact JAX threefry (partitionable) replication.
// R14: instruction diet. Regime settled by R12/R13: R12 (same instrs, better
// source ILP) = null; R13 (+8% instrs via asm, ILP forced) = +8% time ->
// time is PROPORTIONAL to VALU instruction count at fixed ~80% pipe busy.
// => VALU-ISSUE-BOUND at sustained clock ~1.2-1.3 GHz (fully-resident int-
// dense load; cf. m07 pure-FMA sustains only ~1.6 GHz). Latency theory dead.
// Only lever: fewer instrs/element. Cuts vs R11 (~-5/elem, ~7%):
//  (a) add3 injection fusion: x1+=KB; x0 = x0+KA+x1 -> v_add3_u32 (4x, -4)
//  (b) packed slot max: v = (fold & 0xFFFFFE00) | (31-iter); v_max_u32.
//      Replaces shift+cmp+2*cndmask (5) with and/or+max (+1 mov/iter) (~-1.75).
//      Ordering == (max h, tie -> earliest iter) == R11's first-seen rule;
//      j recovered post-loop with one re-load per slot (iter<=31 since
//      ranges <= 8192/256=32 iters). v==0 <=> never-selected == R11 h0=0 init.
// Cross-slot/lane merge keeps exact (h, smaller-j) tie rule. sort_kernel,
// scan_bnd, tail, reduction, finalize: identical to R11. asm REVERTED
// (R13 poison). Intra-kernel spin-sync BANNED (R10). unroll-8 BANNED (R5-R7).

#define B 8192
#define K 1024

struct TFOut { uint32_t a, b; };

__host__ __device__ constexpr uint32_t rotl32(uint32_t x, int r) {
    return (x << r) | (x >> (32 - r));
}

// Full Threefry-2x32 (20 rounds), exactly as jax/_src/prng.py — compile-time
// only, to derive the split keys.
__host__ __device__ constexpr TFOut threefry_full(uint32_t k0, uint32_t k1,
                                                  uint32_t x0, uint32_t x1) {
    const uint32_t ks2 = k0 ^ k1 ^ 0x1BD11BDAu;
    x0 += k0; x1 += k1;
    x0 += x1; x1 = rotl32(x1,13); x1 ^= x0;
    x0 += x1; x1 = rotl32(x1,15); x1 ^= x0;
    x0 += x1; x1 = rotl32(x1,26); x1 ^= x0;
    x0 += x1; x1 = rotl32(x1,6);  x1 ^= x0;
    x0 += k1; x1 += ks2 + 1u;
    x0 += x1; x1 = rotl32(x1,17); x1 ^= x0;
    x0 += x1; x1 = rotl32(x1,29); x1 ^= x0;
    x0 += x1; x1 = rotl32(x1,16); x1 ^= x0;
    x0 += x1; x1 = rotl32(x1,24); x1 ^= x0;
    x0 += ks2; x1 += k0 + 2u;
    x0 += x1; x1 = rotl32(x1,13); x1 ^= x0;
    x0 += x1; x1 = rotl32(x1,15); x1 ^= x0;
    x0 += x1; x1 = rotl32(x1,26); x1 ^= x0;
    x0 += x1; x1 = rotl32(x1,6);  x1 ^= x0;
    x0 += k0; x1 += k1 + 3u;
    x0 += x1; x1 = rotl32(x1,17); x1 ^= x0;
    x0 += x1; x1 = rotl32(x1,29); x1 ^= x0;
    x0 += x1; x1 = rotl32(x1,16); x1 ^= x0;
    x0 += x1; x1 = rotl32(x1,24); x1 ^= x0;
    x0 += k1; x1 += ks2 + 4u;
    x0 += x1; x1 = rotl32(x1,13); x1 ^= x0;
    x0 += x1; x1 = rotl32(x1,15); x1 ^= x0;
    x0 += x1; x1 = rotl32(x1,26); x1 ^= x0;
    x0 += x1; x1 = rotl32(x1,6);  x1 ^= x0;
    x0 += ks2; x1 += k0 + 5u;
    return TFOut{x0, x1};
}

// jax.random.key(42) -> (0,42); partitionable split: kp=block(0,0), kn=block(0,1).
constexpr TFOut KP = threefry_full(0u, 42u, 0u, 0u);
constexpr TFOut KN = threefry_full(0u, 42u, 0u, 1u);

// Scalar device threefry (tail loop + boundary zone only): returns bits>>9-
// comparable value after caller shifts. Identical math to R11's tf_bits.
template<uint32_t TK0, uint32_t TK1>
__device__ __forceinline__ uint32_t tf_bits(uint32_t x1) {
    constexpr uint32_t KS2 = TK0 ^ TK1 ^ 0x1BD11BDAu;
    uint32_t x0 = TK0;
#define RND(r) x0 += x1; x1 = __builtin_amdgcn_alignbit(x1, x1, 32 - (r)); x1 ^= x0;
    RND(13) RND(15) RND(26) RND(6)
    x0 += TK1; x1 += KS2 + 1u;
    RND(17) RND(29) RND(16) RND(24)
    x0 += KS2; x1 += TK0 + 2u;
    RND(13) RND(15) RND(26) RND(6)
    x0 += TK0; x1 += TK1 + 3u;
    RND(17) RND(29) RND(16) RND(24)
    x0 += TK1; x1 += KS2 + 4u;
    RND(13) RND(15) RND(26) RND(6)
    x0 += KS2; x1 += TK0 + 5u;
#undef RND
    return x0 ^ x1;
}

// Main-loop threefry with add3-fused key injections. Bit-identical output to
// tf_bits: x1 gets its injection FIRST, then x0 = x0 + KA + x1 == the
// original (x0 += KA) followed by (x0 += x1) of the next round. Returns the
// raw fold x0^x1 (caller masks).
template<uint32_t TK0, uint32_t TK1>
__device__ __forceinline__ uint32_t tf_fold(uint32_t x1) {
    constexpr uint32_t KS2 = TK0 ^ TK1 ^ 0x1BD11BDAu;
#define ROT(v, S) __builtin_amdgcn_alignbit((v), (v), (S))
    uint32_t x0 = TK0 + x1;            // round 1 add, x0 init folded
    x1 = ROT(x1, 19) ^ x0;             // rotl 13
    x0 += x1; x1 = ROT(x1, 17) ^ x0;   // rotl 15
    x0 += x1; x1 = ROT(x1, 6)  ^ x0;   // rotl 26
    x0 += x1; x1 = ROT(x1, 26) ^ x0;   // rotl 6
    x1 += KS2 + 1u; x0 = x0 + TK1 + x1;   // I1 + round-5 add (v_add3)
    x1 = ROT(x1, 15) ^ x0;             // rotl 17
    x0 += x1; x1 = ROT(x1, 3)  ^ x0;   // rotl 29
    x0 += x1; x1 = ROT(x1, 16) ^ x0;   // rotl 16
    x0 += x1; x1 = ROT(x1, 8)  ^ x0;   // rotl 24
    x1 += TK0 + 2u; x0 = x0 + KS2 + x1;   // I2 + round-9 add
    x1 = ROT(x1, 19) ^ x0;
    x0 += x1; x1 = ROT(x1, 17) ^ x0;
    x0 += x1; x1 = ROT(x1, 6)  ^ x0;
    x0 += x1; x1 = ROT(x1, 26) ^ x0;
    x1 += TK1 + 3u; x0 = x0 + TK0 + x1;   // I3 + round-13 add
    x1 = ROT(x1, 15) ^ x0;
    x0 += x1; x1 = ROT(x1, 3)  ^ x0;
    x0 += x1; x1 = ROT(x1, 16) ^ x0;
    x0 += x1; x1 = ROT(x1, 8)  ^ x0;
    x1 += KS2 + 4u; x0 = x0 + TK1 + x1;   // I4 + round-17 add
    x1 = ROT(x1, 19) ^ x0;
    x0 += x1; x1 = ROT(x1, 17) ^ x0;
    x0 += x1; x1 = ROT(x1, 6)  ^ x0;
    x0 += x1; x1 = ROT(x1, 26) ^ x0;
    x1 += TK0 + 5u; x0 += KS2;            // I5 (final, no following round)
    return x0 ^ x1;
#undef ROT
}

__device__ __forceinline__ void mrg(uint32_t& H, uint32_t& J, uint32_t h2, uint32_t j2) {
    if (h2 > H || (h2 == H && j2 < J)) { H = h2; J = j2; }  // j tie: smaller wins
}

// Unchecked-zone scan: every element passes the predicate by construction.
// Unroll-4, preload next group (over-read past `end` stays inside d_ws).
// Packed accumulator: v = (fold & 0xFFFFFE00) | (31 - iter). max_u32 over v
// == (max h=bits>>9, tie -> earliest iter) == R11's first-seen rule. j is
// recovered post-loop (<= 32 iters, code in [0,31]). v==0 <=> never selected
// (matches R11's h0=0 init: an h==0 element is never chosen; P ~ 2^-23).
template<uint32_t TK0, uint32_t TK1>
__device__ __forceinline__ void scan_main(const uint16_t* __restrict__ idx,
                                          int beg, int end, int lane,
                                          uint32_t kb, uint32_t& H, uint32_t& J)
{
    uint32_t v0 = 0, v1 = 0, v2 = 0, v3 = 0;
    int s = beg;
    uint32_t a = 0, b = 0, c = 0, d = 0;
    if (s + 256 <= end) {
        a = idx[s + lane];       b = idx[s + lane + 64];
        c = idx[s + lane + 128]; d = idx[s + lane + 192];
    }
    uint32_t code = 31u;                       // 31 - iter, wave-uniform
    while (s + 256 <= end) {
        const int sn = s + 256;
        const uint32_t na = idx[sn + lane];        // in flight across hashes
        const uint32_t nb = idx[sn + lane + 64];
        const uint32_t nc = idx[sn + lane + 128];
        const uint32_t nd = idx[sn + lane + 192];
        const uint32_t fa = (tf_fold<TK0, TK1>(a + kb) & 0xFFFFFE00u) | code;
        const uint32_t fb = (tf_fold<TK0, TK1>(b + kb) & 0xFFFFFE00u) | code;
        const uint32_t fc = (tf_fold<TK0, TK1>(c + kb) & 0xFFFFFE00u) | code;
        const uint32_t fd = (tf_fold<TK0, TK1>(d + kb) & 0xFFFFFE00u) | code;
        v0 = v0 > fa ? v0 : fa;                // v_max_u32
        v1 = v1 > fb ? v1 : fb;
        v2 = v2 > fc ? v2 : fc;
        v3 = v3 > fd ? v3 : fd;
        a = na; b = nb; c = nc; d = nd;
        s = sn;
        code -= 1u;
    }
    // Unpack slots -> (h, j); one re-load per non-empty slot (amortized).
    uint32_t hh0 = 0, jj0 = 0xFFFFFFFFu, hh1 = 0, jj1 = 0xFFFFFFFFu;
    uint32_t hh2 = 0, jj2 = 0xFFFFFFFFu, hh3 = 0, jj3 = 0xFFFFFFFFu;
    if (v0) { hh0 = v0 >> 9; jj0 = idx[beg + ((31 - (int)(v0 & 31u)) << 8) + lane]; }
    if (v1) { hh1 = v1 >> 9; jj1 = idx[beg + ((31 - (int)(v1 & 31u)) << 8) + lane + 64]; }
    if (v2) { hh2 = v2 >> 9; jj2 = idx[beg + ((31 - (int)(v2 & 31u)) << 8) + lane + 128]; }
    if (v3) { hh3 = v3 >> 9; jj3 = idx[beg + ((31 - (int)(v3 & 31u)) << 8) + lane + 192]; }
    mrg(hh0, jj0, hh1, jj1); mrg(hh2, jj2, hh3, jj3); mrg(hh0, jj0, hh2, jj2);
    // Tail (< 256 remaining): scalar path, exact (h, smaller-j) merge.
    for (int t = s + lane; t < end; t += 64) {
        const uint32_t j = idx[t];
        const uint32_t hv = tf_bits<TK0, TK1>(j + kb) >> 9;
        if (hv > hh0 || (hv == hh0 && j < jj0)) { hh0 = hv; jj0 = j; }
    }
    mrg(H, J, hh0, jj0);
}

// Boundary zone (~16 elems/row): exact fp32 predicate per element.
template<uint32_t TK0, uint32_t TK1, bool NEG>
__device__ __forceinline__ void scan_bnd(const float* __restrict__ st,
                                         const uint16_t* __restrict__ idx,
                                         int beg, int end, int lane, float ti,
                                         uint32_t kb, uint32_t& H, uint32_t& J,
                                         bool& found)
{
    for (int t = beg + lane; t < end; t += 64) {
        const float tj = st[t];
        const uint32_t j = idx[t];
        const uint32_t hh = tf_bits<TK0, TK1>(j + kb) >> 9;
        const float dd = ti - tj;
        const bool ok = NEG ? (dd > 0.1f) : (dd < -0.1f);
        if (ok) {
            found = true;
            if (hh > H || (hh == H && j < J)) { H = hh; J = j; }
        }
    }
}

// ------------- Kernel A: LDS-staged counting sort + accumulator init --------
// Single block, 1024 threads. Scatter lands in LDS (fast), then dumps to
// global fully coalesced (float4 / uint4).  (byte-identical to R11)
__global__ __launch_bounds__(1024) void sort_kernel(
    const float* __restrict__ targets,
    float* __restrict__ sorted_t, uint16_t* __restrict__ sorted_idx,
    int* __restrict__ bin_start, float* __restrict__ loss_sum,
    float* __restrict__ valid_sum, unsigned int* __restrict__ done)
{
    __shared__ int hist[K];                       //  4 KB
    __shared__ int cursor[K];                     //  4 KB
    __shared__ int wsum[16];
    __shared__ float st_lds[B];                   // 32 KB
    __shared__ __align__(16) uint16_t si_lds[B];  // 16 KB   (total ~56 KB)
    const int tid = threadIdx.x;

    hist[tid] = 0;
    if (tid == 0) { *loss_sum = 0.0f; *valid_sum = 0.0f; *done = 0u; }
    __syncthreads();

    // Load 8 elements/thread as 2x float4 (coalesced).
    const float4* t4 = reinterpret_cast<const float4*>(targets);
    const float4 va = t4[tid];
    const float4 vb = t4[tid + 1024];
    float v[8] = {va.x, va.y, va.z, va.w, vb.x, vb.y, vb.z, vb.w};
    int   bn[8];
#pragma unroll
    for (int i = 0; i < 8; ++i) {
        int b = (int)(v[i] * (float)K);
        b = b < 0 ? 0 : (b > K - 1 ? K - 1 : b);
        bn[i] = b;
        atomicAdd(&hist[b], 1);
    }
    __syncthreads();

    // shfl-based inclusive scan over 1024 bins (1 bin/thread) — proven R8 code.
    const int cnt  = hist[tid];
    const int lane = tid & 63;
    const int wv   = tid >> 6;
    int incl = cnt;
    for (int d = 1; d < 64; d <<= 1) {
        const int o = __shfl_up(incl, d, 64);
        if (lane >= d) incl += o;
    }
    if (lane == 63) wsum[wv] = incl;
    __syncthreads();
    if (tid < 16) {
        int wincl = wsum[tid];
        for (int d = 1; d < 16; d <<= 1) {
            const int o = __shfl_up(wincl, d, 64);
            if (tid >= d) wincl += o;
        }
        wsum[tid] = wincl;
    }
    __syncthreads();
    incl += (wv > 0) ? wsum[wv - 1] : 0;
    bin_start[tid + 1] = incl;
    if (tid == 0) bin_start[0] = 0;
    cursor[tid] = incl - cnt;
    __syncthreads();

    // Scatter into LDS staging (element e for v[i]: i<4 -> 4*tid+i, else 4096+4*tid+i-4).
#pragma unroll
    for (int i = 0; i < 8; ++i) {
        const int e = (i < 4) ? (4 * tid + i) : (4096 + 4 * tid + (i - 4));
        const int p = atomicAdd(&cursor[bn[i]], 1);
        st_lds[p] = v[i];
        si_lds[p] = (uint16_t)e;
    }
    __syncthreads();

    // Coalesced dump to global.
    reinterpret_cast<float4*>(sorted_t)[tid]        = reinterpret_cast<float4*>(st_lds)[tid];
    reinterpret_cast<float4*>(sorted_t)[tid + 1024] = reinterpret_cast<float4*>(st_lds)[tid + 1024];
    reinterpret_cast<uint4*>(sorted_idx)[tid]       = reinterpret_cast<uint4*>(si_lds)[tid];
}

// ------------- Kernel B: per-wave row scan + fused finalize -----------------
// Structure identical to R8/R9/R11; scan_main is the packed-max diet version.
__global__ __launch_bounds__(256) void rows_kernel(
    const float* __restrict__ preds, const float* __restrict__ targets,
    const float* __restrict__ sorted_t, const uint16_t* __restrict__ sorted_idx,
    const int* __restrict__ bin_start,
    float* __restrict__ loss_sum, float* __restrict__ valid_sum,
    unsigned int* __restrict__ done, float* __restrict__ out)
{
    __shared__ float sl[4], sv[4];
    const int lane = threadIdx.x & 63;
    const int wv   = threadIdx.x >> 6;
    const int row  = (blockIdx.x << 2) + wv;

    const float ti = targets[row];
    const uint32_t base = (uint32_t)row << 13;   // row * B

    // Candidate ranges from bins (1e-4 conservative margin >> fp32 ulp slack;
    // boundary zone gets the exact fp32 predicate).
    const float cutn = ti - 0.1f;
    int bl = (int)floorf((cutn - 1e-4f) * (float)K);
    int bh = (int)floorf((cutn + 1e-4f) * (float)K) + 1;
    bl = bl < 0 ? 0 : (bl > K ? K : bl);
    bh = bh < 0 ? 0 : (bh > K ? K : bh);
    const int un_end = bin_start[bl];   // unchecked neg: [0, un_end)
    const int cn_end = bin_start[bh];   // checked  neg: [un_end, cn_end)

    const float cutp = ti + 0.1f;
    int pl = (int)floorf((cutp - 1e-4f) * (float)K);
    int ph = (int)floorf((cutp + 1e-4f) * (float)K) + 1;
    pl = pl < 0 ? 0 : (pl > K ? K : pl);
    ph = ph < 0 ? 0 : (ph > K ? K : ph);
    const int cp_beg = bin_start[pl];   // checked  pos: [cp_beg, up_beg)
    const int up_beg = bin_start[ph];   // unchecked pos: [up_beg, B)

    uint32_t Hn = 0, Jn = 0xFFFFFFFFu;
    bool fn = false;
    scan_main<KN.a, KN.b>(sorted_idx, 0, un_end, lane, base + KN.b, Hn, Jn);
    scan_bnd<KN.a, KN.b, true>(sorted_t, sorted_idx, un_end, cn_end, lane, ti,
                               base + KN.b, Hn, Jn, fn);
    const bool valid_n = (un_end > 0) || __any(fn);

    uint32_t Hp = 0, Jp = 0xFFFFFFFFu;
    bool fp2 = false;
    scan_main<KP.a, KP.b>(sorted_idx, up_beg, B, lane, base + KP.b, Hp, Jp);
    scan_bnd<KP.a, KP.b, false>(sorted_t, sorted_idx, cp_beg, up_beg, lane, ti,
                                base + KP.b, Hp, Jp, fp2);
    const bool valid_p = (up_beg < B) || __any(fp2);

    // In-wave (h, j) max-reduction with first-index tie-break.
    for (int off = 32; off > 0; off >>= 1) {
        const uint32_t ohn = __shfl_down(Hn, off, 64);
        const uint32_t ojn = __shfl_down(Jn, off, 64);
        if (ohn > Hn || (ohn == Hn && ojn < Jn)) { Hn = ohn; Jn = ojn; }
        const uint32_t ohp = __shfl_down(Hp, off, 64);
        const uint32_t ojp = __shfl_down(Jp, off, 64);
        if (ohp > Hp || (ohp == Hp && ojp < Jp)) { Hp = ohp; Jp = ojp; }
    }

    if (lane == 0) {
        float loss = 0.0f, valid = 0.0f;
        if (valid_n && valid_p) {
            const float per = 0.5f - (preds[Jp & 8191u] - preds[Jn & 8191u]);
            loss = per > 0.0f ? per : 0.0f;
            valid = 1.0f;
        }
        sl[wv] = loss; sv[wv] = valid;
    }
    __syncthreads();
    if (threadIdx.x == 0) {
        atomicAdd(loss_sum,  sl[0] + sl[1] + sl[2] + sl[3]);
        atomicAdd(valid_sum, sv[0] + sv[1] + sv[2] + sv[3]);
        __threadfence();
        const unsigned int old = atomicAdd(done, 1u);
        if (old == gridDim.x - 1u) {          // last block finalizes
            const float ls = atomicAdd(loss_sum, 0.0f);
            const float vs = atomicAdd(valid_sum, 0.0f);
            out[0] = vs > 0.0f ? ls / fmaxf(vs, 1.0f) : 0.0f;
        }
    }
}

extern "C" void kernel_launch(void* const* d_in, const int* in_sizes, int n_in,
                              void* d_out, int out_size, void* d_ws, size_t ws_size,
                              hipStream_t stream) {
    const float* preds   = (const float*)d_in[0];
    const float* targets = (const float*)d_in[1];

    // Layout identical to R4/R8 (proven): watermark ~57.4 KB. The 256 words
    // (512 u16 entries) after sorted_idx are the unroll-4 over-read slack.
    float* ws = (float*)d_ws;
    float*        sorted_t   = ws;                       // B floats
    uint16_t*     sorted_idx = (uint16_t*)(ws + B);      // B u16 + slack
    int*          bin_start  = (int*)(ws + B + B / 2 + 256); // K+1 ints
    float*        loss_sum   = ws + B + B / 2 + 2048;
    float*        valid_sum  = loss_sum + 1;
    unsigned int* done       = (unsigned int*)(loss_sum + 2);

    sort_kernel<<<1, 1024, 0, stream>>>(targets, sorted_t, sorted_idx, bin_start,
                                        loss_sum, valid_sum, done);
    rows_kernel<<<B / 4, 256, 0, stream>>>(preds, targets, sorted_t, sorted_idx,
                                           bin_start, loss_sum, valid_sum, done,
                                           (float*)d_out);
}

// Round 4
// 177.774 us; speedup vs baseline: 1.0268x; 1.0030x over previous
//
#include <hip/hip_runtime.h>
#include <stdint.h>

// TripletRankingLoss, bit-exact JAX threefry (partitionable) replication.
// R15: isolate R14's bundled variables. R14 = tf_fold restructure (a) +
// packed-max update (b) -> +4.4% aggregate. Suspect (a): v_add3_u32 is VOP3
// (no literals) so the hand-reorder likely lost the compiler's own folds
// (R13 lesson: R11's hash codegen is a delicate local optimum). R15 keeps
// R11's tf_bits BYTE-IDENTICAL and applies ONLY (b): slot update
// lshr+cmp+2*cndmask (4 ops) -> v_and_or_b32+v_max_u32 (2 ops + amortized
// code decrement). Packed v = (bits & 0xFFFFFE00) | (31-iter): max == (max
// h=bits>>9, tie -> earliest iter) == R11 first-seen; j recovered post-loop
// by one re-load per slot (<=32 iters/scan since ranges <= 8192, 256/iter).
// v==0 <=> never-selected == R11 h0=0 init. Unpack/tail structure carried
// verbatim from R14 (ran bit-exact, absmax=0). Regime (R12/R13 confirmed):
// time PROPORTIONAL to VALU instr count, ~80% pipe busy, sustained clock
// ~1.2-1.3 GHz. Pre-committed: rows<=125 -> continue diet; rows>=127 ->
// revert to R11, declare instruction floor / roofline.
// tf_fold REVERTED (R14 poison). asm REVERTED (R13 poison). Intra-kernel
// spin-sync BANNED (R10). unroll-8 BANNED (R5-R7).

#define B 8192
#define K 1024

struct TFOut { uint32_t a, b; };

__host__ __device__ constexpr uint32_t rotl32(uint32_t x, int r) {
    return (x << r) | (x >> (32 - r));
}

// Full Threefry-2x32 (20 rounds), exactly as jax/_src/prng.py — compile-time
// only, to derive the split keys.
__host__ __device__ constexpr TFOut threefry_full(uint32_t k0, uint32_t k1,
                                                  uint32_t x0, uint32_t x1) {
    const uint32_t ks2 = k0 ^ k1 ^ 0x1BD11BDAu;
    x0 += k0; x1 += k1;
    x0 += x1; x1 = rotl32(x1,13); x1 ^= x0;
    x0 += x1; x1 = rotl32(x1,15); x1 ^= x0;
    x0 += x1; x1 = rotl32(x1,26); x1 ^= x0;
    x0 += x1; x1 = rotl32(x1,6);  x1 ^= x0;
    x0 += k1; x1 += ks2 + 1u;
    x0 += x1; x1 = rotl32(x1,17); x1 ^= x0;
    x0 += x1; x1 = rotl32(x1,29); x1 ^= x0;
    x0 += x1; x1 = rotl32(x1,16); x1 ^= x0;
    x0 += x1; x1 = rotl32(x1,24); x1 ^= x0;
    x0 += ks2; x1 += k0 + 2u;
    x0 += x1; x1 = rotl32(x1,13); x1 ^= x0;
    x0 += x1; x1 = rotl32(x1,15); x1 ^= x0;
    x0 += x1; x1 = rotl32(x1,26); x1 ^= x0;
    x0 += x1; x1 = rotl32(x1,6);  x1 ^= x0;
    x0 += k0; x1 += k1 + 3u;
    x0 += x1; x1 = rotl32(x1,17); x1 ^= x0;
    x0 += x1; x1 = rotl32(x1,29); x1 ^= x0;
    x0 += x1; x1 = rotl32(x1,16); x1 ^= x0;
    x0 += x1; x1 = rotl32(x1,24); x1 ^= x0;
    x0 += k1; x1 += ks2 + 4u;
    x0 += x1; x1 = rotl32(x1,13); x1 ^= x0;
    x0 += x1; x1 = rotl32(x1,15); x1 ^= x0;
    x0 += x1; x1 = rotl32(x1,26); x1 ^= x0;
    x0 += x1; x1 = rotl32(x1,6);  x1 ^= x0;
    x0 += ks2; x1 += k0 + 5u;
    return TFOut{x0, x1};
}

// jax.random.key(42) -> (0,42); partitionable split: kp=block(0,0), kn=block(0,1).
constexpr TFOut KP = threefry_full(0u, 42u, 0u, 0u);
constexpr TFOut KN = threefry_full(0u, 42u, 0u, 1u);

// Device threefry, R11-identical codegen (DO NOT restructure — R13/R14
// showed the compiler's folds here are fragile). Returns raw x0^x1.
template<uint32_t TK0, uint32_t TK1>
__device__ __forceinline__ uint32_t tf_bits(uint32_t x1) {
    constexpr uint32_t KS2 = TK0 ^ TK1 ^ 0x1BD11BDAu;
    uint32_t x0 = TK0;
#define RND(r) x0 += x1; x1 = __builtin_amdgcn_alignbit(x1, x1, 32 - (r)); x1 ^= x0;
    RND(13) RND(15) RND(26) RND(6)
    x0 += TK1; x1 += KS2 + 1u;
    RND(17) RND(29) RND(16) RND(24)
    x0 += KS2; x1 += TK0 + 2u;
    RND(13) RND(15) RND(26) RND(6)
    x0 += TK0; x1 += TK1 + 3u;
    RND(17) RND(29) RND(16) RND(24)
    x0 += TK1; x1 += KS2 + 4u;
    RND(13) RND(15) RND(26) RND(6)
    x0 += KS2; x1 += TK0 + 5u;
#undef RND
    return x0 ^ x1;
}

__device__ __forceinline__ void mrg(uint32_t& H, uint32_t& J, uint32_t h2, uint32_t j2) {
    if (h2 > H || (h2 == H && j2 < J)) { H = h2; J = j2; }  // j tie: smaller wins
}

// Unchecked-zone scan: every element passes the predicate by construction.
// Unroll-4, preload next group (over-read past `end` stays inside d_ws).
// Packed accumulator: v = (bits & 0xFFFFFE00) | (31 - iter) -> v_and_or_b32;
// v_max_u32 == (max h=bits>>9, tie -> earliest iter) == R11 first-seen rule.
template<uint32_t TK0, uint32_t TK1>
__device__ __forceinline__ void scan_main(const uint16_t* __restrict__ idx,
                                          int beg, int end, int lane,
                                          uint32_t kb, uint32_t& H, uint32_t& J)
{
    uint32_t v0 = 0, v1 = 0, v2 = 0, v3 = 0;
    int s = beg;
    uint32_t a = 0, b = 0, c = 0, d = 0;
    if (s + 256 <= end) {
        a = idx[s + lane];       b = idx[s + lane + 64];
        c = idx[s + lane + 128]; d = idx[s + lane + 192];
    }
    uint32_t code = 31u;                       // 31 - iter, wave-uniform
    while (s + 256 <= end) {
        const int sn = s + 256;
        const uint32_t na = idx[sn + lane];        // in flight across hashes
        const uint32_t nb = idx[sn + lane + 64];
        const uint32_t nc = idx[sn + lane + 128];
        const uint32_t nd = idx[sn + lane + 192];
        const uint32_t fa = (tf_bits<TK0, TK1>(a + kb) & 0xFFFFFE00u) | code;
        const uint32_t fb = (tf_bits<TK0, TK1>(b + kb) & 0xFFFFFE00u) | code;
        const uint32_t fc = (tf_bits<TK0, TK1>(c + kb) & 0xFFFFFE00u) | code;
        const uint32_t fd = (tf_bits<TK0, TK1>(d + kb) & 0xFFFFFE00u) | code;
        v0 = v0 > fa ? v0 : fa;                // v_max_u32
        v1 = v1 > fb ? v1 : fb;
        v2 = v2 > fc ? v2 : fc;
        v3 = v3 > fd ? v3 : fd;
        a = na; b = nb; c = nc; d = nd;
        s = sn;
        code -= 1u;
    }
    // Unpack slots -> (h, j); one re-load per non-empty slot (amortized).
    uint32_t hh0 = 0, jj0 = 0xFFFFFFFFu, hh1 = 0, jj1 = 0xFFFFFFFFu;
    uint32_t hh2 = 0, jj2 = 0xFFFFFFFFu, hh3 = 0, jj3 = 0xFFFFFFFFu;
    if (v0) { hh0 = v0 >> 9; jj0 = idx[beg + ((31 - (int)(v0 & 31u)) << 8) + lane]; }
    if (v1) { hh1 = v1 >> 9; jj1 = idx[beg + ((31 - (int)(v1 & 31u)) << 8) + lane + 64]; }
    if (v2) { hh2 = v2 >> 9; jj2 = idx[beg + ((31 - (int)(v2 & 31u)) << 8) + lane + 128]; }
    if (v3) { hh3 = v3 >> 9; jj3 = idx[beg + ((31 - (int)(v3 & 31u)) << 8) + lane + 192]; }
    mrg(hh0, jj0, hh1, jj1); mrg(hh2, jj2, hh3, jj3); mrg(hh0, jj0, hh2, jj2);
    // Tail (< 256 remaining): scalar path, exact (h, smaller-j) merge.
    for (int t = s + lane; t < end; t += 64) {
        const uint32_t j = idx[t];
        const uint32_t hv = tf_bits<TK0, TK1>(j + kb) >> 9;
        if (hv > hh0 || (hv == hh0 && j < jj0)) { hh0 = hv; jj0 = j; }
    }
    mrg(H, J, hh0, jj0);
}

// Boundary zone (~16 elems/row): exact fp32 predicate per element.
template<uint32_t TK0, uint32_t TK1, bool NEG>
__device__ __forceinline__ void scan_bnd(const float* __restrict__ st,
                                         const uint16_t* __restrict__ idx,
                                         int beg, int end, int lane, float ti,
                                         uint32_t kb, uint32_t& H, uint32_t& J,
                                         bool& found)
{
    for (int t = beg + lane; t < end; t += 64) {
        const float tj = st[t];
        const uint32_t j = idx[t];
        const uint32_t hh = tf_bits<TK0, TK1>(j + kb) >> 9;
        const float dd = ti - tj;
        const bool ok = NEG ? (dd > 0.1f) : (dd < -0.1f);
        if (ok) {
            found = true;
            if (hh > H || (hh == H && j < J)) { H = hh; J = j; }
        }
    }
}

// ------------- Kernel A: LDS-staged counting sort + accumulator init --------
// Single block, 1024 threads. Scatter lands in LDS (fast), then dumps to
// global fully coalesced (float4 / uint4).  (byte-identical to R11)
__global__ __launch_bounds__(1024) void sort_kernel(
    const float* __restrict__ targets,
    float* __restrict__ sorted_t, uint16_t* __restrict__ sorted_idx,
    int* __restrict__ bin_start, float* __restrict__ loss_sum,
    float* __restrict__ valid_sum, unsigned int* __restrict__ done)
{
    __shared__ int hist[K];                       //  4 KB
    __shared__ int cursor[K];                     //  4 KB
    __shared__ int wsum[16];
    __shared__ float st_lds[B];                   // 32 KB
    __shared__ __align__(16) uint16_t si_lds[B];  // 16 KB   (total ~56 KB)
    const int tid = threadIdx.x;

    hist[tid] = 0;
    if (tid == 0) { *loss_sum = 0.0f; *valid_sum = 0.0f; *done = 0u; }
    __syncthreads();

    // Load 8 elements/thread as 2x float4 (coalesced).
    const float4* t4 = reinterpret_cast<const float4*>(targets);
    const float4 va = t4[tid];
    const float4 vb = t4[tid + 1024];
    float v[8] = {va.x, va.y, va.z, va.w, vb.x, vb.y, vb.z, vb.w};
    int   bn[8];
#pragma unroll
    for (int i = 0; i < 8; ++i) {
        int b = (int)(v[i] * (float)K);
        b = b < 0 ? 0 : (b > K - 1 ? K - 1 : b);
        bn[i] = b;
        atomicAdd(&hist[b], 1);
    }
    __syncthreads();

    // shfl-based inclusive scan over 1024 bins (1 bin/thread) — proven R8 code.
    const int cnt  = hist[tid];
    const int lane = tid & 63;
    const int wv   = tid >> 6;
    int incl = cnt;
    for (int d = 1; d < 64; d <<= 1) {
        const int o = __shfl_up(incl, d, 64);
        if (lane >= d) incl += o;
    }
    if (lane == 63) wsum[wv] = incl;
    __syncthreads();
    if (tid < 16) {
        int wincl = wsum[tid];
        for (int d = 1; d < 16; d <<= 1) {
            const int o = __shfl_up(wincl, d, 64);
            if (tid >= d) wincl += o;
        }
        wsum[tid] = wincl;
    }
    __syncthreads();
    incl += (wv > 0) ? wsum[wv - 1] : 0;
    bin_start[tid + 1] = incl;
    if (tid == 0) bin_start[0] = 0;
    cursor[tid] = incl - cnt;
    __syncthreads();

    // Scatter into LDS staging (element e for v[i]: i<4 -> 4*tid+i, else 4096+4*tid+i-4).
#pragma unroll
    for (int i = 0; i < 8; ++i) {
        const int e = (i < 4) ? (4 * tid + i) : (4096 + 4 * tid + (i - 4));
        const int p = atomicAdd(&cursor[bn[i]], 1);
        st_lds[p] = v[i];
        si_lds[p] = (uint16_t)e;
    }
    __syncthreads();

    // Coalesced dump to global.
    reinterpret_cast<float4*>(sorted_t)[tid]        = reinterpret_cast<float4*>(st_lds)[tid];
    reinterpret_cast<float4*>(sorted_t)[tid + 1024] = reinterpret_cast<float4*>(st_lds)[tid + 1024];
    reinterpret_cast<uint4*>(sorted_idx)[tid]       = reinterpret_cast<uint4*>(si_lds)[tid];
}

// ------------- Kernel B: per-wave row scan + fused finalize -----------------
// Structure identical to R8/R9/R11; scan_main has the packed-max update only.
__global__ __launch_bounds__(256) void rows_kernel(
    const float* __restrict__ preds, const float* __restrict__ targets,
    const float* __restrict__ sorted_t, const uint16_t* __restrict__ sorted_idx,
    const int* __restrict__ bin_start,
    float* __restrict__ loss_sum, float* __restrict__ valid_sum,
    unsigned int* __restrict__ done, float* __restrict__ out)
{
    __shared__ float sl[4], sv[4];
    const int lane = threadIdx.x & 63;
    const int wv   = threadIdx.x >> 6;
    const int row  = (blockIdx.x << 2) + wv;

    const float ti = targets[row];
    const uint32_t base = (uint32_t)row << 13;   // row * B

    // Candidate ranges from bins (1e-4 conservative margin >> fp32 ulp slack;
    // boundary zone gets the exact fp32 predicate).
    const float cutn = ti - 0.1f;
    int bl = (int)floorf((cutn - 1e-4f) * (float)K);
    int bh = (int)floorf((cutn + 1e-4f) * (float)K) + 1;
    bl = bl < 0 ? 0 : (bl > K ? K : bl);
    bh = bh < 0 ? 0 : (bh > K ? K : bh);
    const int un_end = bin_start[bl];   // unchecked neg: [0, un_end)
    const int cn_end = bin_start[bh];   // checked  neg: [un_end, cn_end)

    const float cutp = ti + 0.1f;
    int pl = (int)floorf((cutp - 1e-4f) * (float)K);
    int ph = (int)floorf((cutp + 1e-4f) * (float)K) + 1;
    pl = pl < 0 ? 0 : (pl > K ? K : pl);
    ph = ph < 0 ? 0 : (ph > K ? K : ph);
    const int cp_beg = bin_start[pl];   // checked  pos: [cp_beg, up_beg)
    const int up_beg = bin_start[ph];   // unchecked pos: [up_beg, B)

    uint32_t Hn = 0, Jn = 0xFFFFFFFFu;
    bool fn = false;
    scan_main<KN.a, KN.b>(sorted_idx, 0, un_end, lane, base + KN.b, Hn, Jn);
    scan_bnd<KN.a, KN.b, true>(sorted_t, sorted_idx, un_end, cn_end, lane, ti,
                               base + KN.b, Hn, Jn, fn);
    const bool valid_n = (un_end > 0) || __any(fn);

    uint32_t Hp = 0, Jp = 0xFFFFFFFFu;
    bool fp2 = false;
    scan_main<KP.a, KP.b>(sorted_idx, up_beg, B, lane, base + KP.b, Hp, Jp);
    scan_bnd<KP.a, KP.b, false>(sorted_t, sorted_idx, cp_beg, up_beg, lane, ti,
                                base + KP.b, Hp, Jp, fp2);
    const bool valid_p = (up_beg < B) || __any(fp2);

    // In-wave (h, j) max-reduction with first-index tie-break.
    for (int off = 32; off > 0; off >>= 1) {
        const uint32_t ohn = __shfl_down(Hn, off, 64);
        const uint32_t ojn = __shfl_down(Jn, off, 64);
        if (ohn > Hn || (ohn == Hn && ojn < Jn)) { Hn = ohn; Jn = ojn; }
        const uint32_t ohp = __shfl_down(Hp, off, 64);
        const uint32_t ojp = __shfl_down(Jp, off, 64);
        if (ohp > Hp || (ohp == Hp && ojp < Jp)) { Hp = ohp; Jp = ojp; }
    }

    if (lane == 0) {
        float loss = 0.0f, valid = 0.0f;
        if (valid_n && valid_p) {
            const float per = 0.5f - (preds[Jp & 8191u] - preds[Jn & 8191u]);
            loss = per > 0.0f ? per : 0.0f;
            valid = 1.0f;
        }
        sl[wv] = loss; sv[wv] = valid;
    }
    __syncthreads();
    if (threadIdx.x == 0) {
        atomicAdd(loss_sum,  sl[0] + sl[1] + sl[2] + sl[3]);
        atomicAdd(valid_sum, sv[0] + sv[1] + sv[2] + sv[3]);
        __threadfence();
        const unsigned int old = atomicAdd(done, 1u);
        if (old == gridDim.x - 1u) {          // last block finalizes
            const float ls = atomicAdd(loss_sum, 0.0f);
            const float vs = atomicAdd(valid_sum, 0.0f);
            out[0] = vs > 0.0f ? ls / fmaxf(vs, 1.0f) : 0.0f;
        }
    }
}

extern "C" void kernel_launch(void* const* d_in, const int* in_sizes, int n_in,
                              void* d_out, int out_size, void* d_ws, size_t ws_size,
                              hipStream_t stream) {
    const float* preds   = (const float*)d_in[0];
    const float* targets = (const float*)d_in[1];

    // Layout identical to R4/R8 (proven): watermark ~57.4 KB. The 256 words
    // (512 u16 entries) after sorted_idx are the unroll-4 over-read slack.
    float* ws = (float*)d_ws;
    float*        sorted_t   = ws;                       // B floats
    uint16_t*     sorted_idx = (uint16_t*)(ws + B);      // B u16 + slack
    int*          bin_start  = (int*)(ws + B + B / 2 + 256); // K+1 ints
    float*        loss_sum   = ws + B + B / 2 + 2048;
    float*        valid_sum  = loss_sum + 1;
    unsigned int* done       = (unsigned int*)(loss_sum + 2);

    sort_kernel<<<1, 1024, 0, stream>>>(targets, sorted_t, sorted_idx, bin_start,
                                        loss_sum, valid_sum, done);
    rows_kernel<<<B / 4, 256, 0, stream>>>(preds, targets, sorted_t, sorted_idx,
                                           bin_start, loss_sum, valid_sum, done,
                                           (float*)d_out);
}

// Round 5
// 173.423 us; speedup vs baseline: 1.0526x; 1.0251x over previous
//
#include <hip/hip_runtime.h>
#include <stdint.h>

// TripletRankingLoss, bit-exact JAX threefry (partitionable) replication.
// R16: REVERT to R11 byte-for-byte (code identical; this comment is the only
// change). Search concluded; ledger:
//   R12 C++ 4-stream ILP interleave        -> 0%    (TLP already saturates)
//   R13 asm-pinned ILP (+8% instrs)        -> +8%   (time PROPORTIONAL to
//                                                    VALU instr count)
//   R14 algebraic refold + packed-max      -> +4.4% (lost compiler folds)
//   R15 packed-max isolated                -> +5%   (and_or/max didn't form;
//                                                    epilogue gathers)
// Conclusion: R11 is the instruction/schedule optimum reachable from source.
// Arithmetic: 54.3M forced hashes (bit-exact threefry per valid (i,j) pair,
// 0.81*B^2) x ~79 VALU/elem (~73 algorithmic floor: 20 rounds x 3 + inject +
// fold) / 64 lanes / 1024 SIMDs x 2 cyc = ~129K pipe-cycles/SIMD; at ~82%
// VALU busy and ~1.29 GHz sustained -> ~127us rows. Measured 126.7-127.4.
// Remaining: ~18% busy-gap (unattributable with available counters) + ~47us
// sort+dispatch (fusion blocked: 56KB LDS sort phase would cap occupancy;
// redundant per-block sort doesn't amortize; spin-sync BANNED R10 3.4x).
// tf_fold BANNED (R14). asm BANNED (R13). packed-max BANNED (R15).
// Intra-kernel spin-sync BANNED (R10). unroll-8 BANNED (R5-R7).

#define B 8192
#define K 1024

struct TFOut { uint32_t a, b; };

__host__ __device__ constexpr uint32_t rotl32(uint32_t x, int r) {
    return (x << r) | (x >> (32 - r));
}

// Full Threefry-2x32 (20 rounds), exactly as jax/_src/prng.py — compile-time
// only, to derive the split keys.
__host__ __device__ constexpr TFOut threefry_full(uint32_t k0, uint32_t k1,
                                                  uint32_t x0, uint32_t x1) {
    const uint32_t ks2 = k0 ^ k1 ^ 0x1BD11BDAu;
    x0 += k0; x1 += k1;
    x0 += x1; x1 = rotl32(x1,13); x1 ^= x0;
    x0 += x1; x1 = rotl32(x1,15); x1 ^= x0;
    x0 += x1; x1 = rotl32(x1,26); x1 ^= x0;
    x0 += x1; x1 = rotl32(x1,6);  x1 ^= x0;
    x0 += k1; x1 += ks2 + 1u;
    x0 += x1; x1 = rotl32(x1,17); x1 ^= x0;
    x0 += x1; x1 = rotl32(x1,29); x1 ^= x0;
    x0 += x1; x1 = rotl32(x1,16); x1 ^= x0;
    x0 += x1; x1 = rotl32(x1,24); x1 ^= x0;
    x0 += ks2; x1 += k0 + 2u;
    x0 += x1; x1 = rotl32(x1,13); x1 ^= x0;
    x0 += x1; x1 = rotl32(x1,15); x1 ^= x0;
    x0 += x1; x1 = rotl32(x1,26); x1 ^= x0;
    x0 += x1; x1 = rotl32(x1,6);  x1 ^= x0;
    x0 += k0; x1 += k1 + 3u;
    x0 += x1; x1 = rotl32(x1,17); x1 ^= x0;
    x0 += x1; x1 = rotl32(x1,29); x1 ^= x0;
    x0 += x1; x1 = rotl32(x1,16); x1 ^= x0;
    x0 += x1; x1 = rotl32(x1,24); x1 ^= x0;
    x0 += k1; x1 += ks2 + 4u;
    x0 += x1; x1 = rotl32(x1,13); x1 ^= x0;
    x0 += x1; x1 = rotl32(x1,15); x1 ^= x0;
    x0 += x1; x1 = rotl32(x1,26); x1 ^= x0;
    x0 += x1; x1 = rotl32(x1,6);  x1 ^= x0;
    x0 += ks2; x1 += k0 + 5u;
    return TFOut{x0, x1};
}

// jax.random.key(42) -> (0,42); partitionable split: kp=block(0,0), kn=block(0,1).
constexpr TFOut KP = threefry_full(0u, 42u, 0u, 0u);
constexpr TFOut KN = threefry_full(0u, 42u, 0u, 1u);

// Device-fast threefry: x0=0 implicit, keys compile-time, caller passes
// x1 pre-keyed (= f + K1). alignbit guarantees 1-inst rotates.
template<uint32_t TK0, uint32_t TK1>
__device__ __forceinline__ uint32_t tf_bits(uint32_t x1) {
    constexpr uint32_t KS2 = TK0 ^ TK1 ^ 0x1BD11BDAu;
    uint32_t x0 = TK0;
#define RND(r) x0 += x1; x1 = __builtin_amdgcn_alignbit(x1, x1, 32 - (r)); x1 ^= x0;
    RND(13) RND(15) RND(26) RND(6)
    x0 += TK1; x1 += KS2 + 1u;
    RND(17) RND(29) RND(16) RND(24)
    x0 += KS2; x1 += TK0 + 2u;
    RND(13) RND(15) RND(26) RND(6)
    x0 += TK0; x1 += TK1 + 3u;
    RND(17) RND(29) RND(16) RND(24)
    x0 += TK1; x1 += KS2 + 4u;
    RND(13) RND(15) RND(26) RND(6)
    x0 += KS2; x1 += TK0 + 5u;
#undef RND
    return x0 ^ x1;
}

__device__ __forceinline__ void mrg(uint32_t& H, uint32_t& J, uint32_t h2, uint32_t j2) {
    if (h2 > H || (h2 == H && j2 < J)) { H = h2; J = j2; }  // j tie: smaller wins
}

// Unchecked-zone scan: every element passes the predicate by construction.
// Unroll-4, preload next group (over-read past `end` stays inside d_ws).
template<uint32_t TK0, uint32_t TK1>
__device__ __forceinline__ void scan_main(const uint16_t* __restrict__ idx,
                                          int beg, int end, int lane,
                                          uint32_t kb, uint32_t& H, uint32_t& J)
{
    uint32_t h0 = 0, h1 = 0, h2 = 0, h3 = 0;
    uint32_t j0 = 0xFFFFFFFFu, j1 = 0xFFFFFFFFu, j2 = 0xFFFFFFFFu, j3 = 0xFFFFFFFFu;
    int s = beg;
    uint32_t a = 0, b = 0, c = 0, d = 0;
    if (s + 256 <= end) {
        a = idx[s + lane];       b = idx[s + lane + 64];
        c = idx[s + lane + 128]; d = idx[s + lane + 192];
    }
    while (s + 256 <= end) {
        const int sn = s + 256;
        const uint32_t na = idx[sn + lane];        // in flight across the 4 hashes
        const uint32_t nb = idx[sn + lane + 64];
        const uint32_t nc = idx[sn + lane + 128];
        const uint32_t nd = idx[sn + lane + 192];
        const uint32_t ha = tf_bits<TK0, TK1>(a + kb) >> 9;
        const uint32_t hb = tf_bits<TK0, TK1>(b + kb) >> 9;
        const uint32_t hc = tf_bits<TK0, TK1>(c + kb) >> 9;
        const uint32_t hd = tf_bits<TK0, TK1>(d + kb) >> 9;
        if (ha > h0) { h0 = ha; j0 = a; }
        if (hb > h1) { h1 = hb; j1 = b; }
        if (hc > h2) { h2 = hc; j2 = c; }
        if (hd > h3) { h3 = hd; j3 = d; }
        a = na; b = nb; c = nc; d = nd;
        s = sn;
    }
    for (int t = s + lane; t < end; t += 64) {
        const uint32_t j = idx[t];
        const uint32_t hh = tf_bits<TK0, TK1>(j + kb) >> 9;
        if (hh > h0) { h0 = hh; j0 = j; }
    }
    mrg(h0, j0, h1, j1); mrg(h2, j2, h3, j3); mrg(h0, j0, h2, j2);
    mrg(H, J, h0, j0);
}

// Boundary zone (~16 elems/row): exact fp32 predicate per element.
template<uint32_t TK0, uint32_t TK1, bool NEG>
__device__ __forceinline__ void scan_bnd(const float* __restrict__ st,
                                         const uint16_t* __restrict__ idx,
                                         int beg, int end, int lane, float ti,
                                         uint32_t kb, uint32_t& H, uint32_t& J,
                                         bool& found)
{
    for (int t = beg + lane; t < end; t += 64) {
        const float tj = st[t];
        const uint32_t j = idx[t];
        const uint32_t hh = tf_bits<TK0, TK1>(j + kb) >> 9;
        const float dd = ti - tj;
        const bool ok = NEG ? (dd > 0.1f) : (dd < -0.1f);
        if (ok) {
            found = true;
            if (hh > H || (hh == H && j < J)) { H = hh; J = j; }
        }
    }
}

// ------------- Kernel A: LDS-staged counting sort + accumulator init --------
// Single block, 1024 threads. Scatter lands in LDS (fast), then dumps to
// global fully coalesced (float4 / uint4).
__global__ __launch_bounds__(1024) void sort_kernel(
    const float* __restrict__ targets,
    float* __restrict__ sorted_t, uint16_t* __restrict__ sorted_idx,
    int* __restrict__ bin_start, float* __restrict__ loss_sum,
    float* __restrict__ valid_sum, unsigned int* __restrict__ done)
{
    __shared__ int hist[K];                       //  4 KB
    __shared__ int cursor[K];                     //  4 KB
    __shared__ int wsum[16];
    __shared__ float st_lds[B];                   // 32 KB
    __shared__ __align__(16) uint16_t si_lds[B];  // 16 KB   (total ~56 KB)
    const int tid = threadIdx.x;

    hist[tid] = 0;
    if (tid == 0) { *loss_sum = 0.0f; *valid_sum = 0.0f; *done = 0u; }
    __syncthreads();

    // Load 8 elements/thread as 2x float4 (coalesced).
    const float4* t4 = reinterpret_cast<const float4*>(targets);
    const float4 va = t4[tid];
    const float4 vb = t4[tid + 1024];
    float v[8] = {va.x, va.y, va.z, va.w, vb.x, vb.y, vb.z, vb.w};
    int   bn[8];
#pragma unroll
    for (int i = 0; i < 8; ++i) {
        int b = (int)(v[i] * (float)K);
        b = b < 0 ? 0 : (b > K - 1 ? K - 1 : b);
        bn[i] = b;
        atomicAdd(&hist[b], 1);
    }
    __syncthreads();

    // shfl-based inclusive scan over 1024 bins (1 bin/thread) — proven R8 code.
    const int cnt  = hist[tid];
    const int lane = tid & 63;
    const int wv   = tid >> 6;
    int incl = cnt;
    for (int d = 1; d < 64; d <<= 1) {
        const int o = __shfl_up(incl, d, 64);
        if (lane >= d) incl += o;
    }
    if (lane == 63) wsum[wv] = incl;
    __syncthreads();
    if (tid < 16) {
        int wincl = wsum[tid];
        for (int d = 1; d < 16; d <<= 1) {
            const int o = __shfl_up(wincl, d, 64);
            if (tid >= d) wincl += o;
        }
        wsum[tid] = wincl;
    }
    __syncthreads();
    incl += (wv > 0) ? wsum[wv - 1] : 0;
    bin_start[tid + 1] = incl;
    if (tid == 0) bin_start[0] = 0;
    cursor[tid] = incl - cnt;
    __syncthreads();

    // Scatter into LDS staging (element e for v[i]: i<4 -> 4*tid+i, else 4096+4*tid+i-4).
#pragma unroll
    for (int i = 0; i < 8; ++i) {
        const int e = (i < 4) ? (4 * tid + i) : (4096 + 4 * tid + (i - 4));
        const int p = atomicAdd(&cursor[bn[i]], 1);
        st_lds[p] = v[i];
        si_lds[p] = (uint16_t)e;
    }
    __syncthreads();

    // Coalesced dump to global.
    reinterpret_cast<float4*>(sorted_t)[tid]        = reinterpret_cast<float4*>(st_lds)[tid];
    reinterpret_cast<float4*>(sorted_t)[tid + 1024] = reinterpret_cast<float4*>(st_lds)[tid + 1024];
    reinterpret_cast<uint4*>(sorted_idx)[tid]       = reinterpret_cast<uint4*>(si_lds)[tid];
}

// ------------- Kernel B: per-wave row scan + fused finalize -----------------
// (byte-identical to R8/R9/R11's passing rows_kernel)
__global__ __launch_bounds__(256) void rows_kernel(
    const float* __restrict__ preds, const float* __restrict__ targets,
    const float* __restrict__ sorted_t, const uint16_t* __restrict__ sorted_idx,
    const int* __restrict__ bin_start,
    float* __restrict__ loss_sum, float* __restrict__ valid_sum,
    unsigned int* __restrict__ done, float* __restrict__ out)
{
    __shared__ float sl[4], sv[4];
    const int lane = threadIdx.x & 63;
    const int wv   = threadIdx.x >> 6;
    const int row  = (blockIdx.x << 2) + wv;

    const float ti = targets[row];
    const uint32_t base = (uint32_t)row << 13;   // row * B

    // Candidate ranges from bins (1e-4 conservative margin >> fp32 ulp slack;
    // boundary zone gets the exact fp32 predicate).
    const float cutn = ti - 0.1f;
    int bl = (int)floorf((cutn - 1e-4f) * (float)K);
    int bh = (int)floorf((cutn + 1e-4f) * (float)K) + 1;
    bl = bl < 0 ? 0 : (bl > K ? K : bl);
    bh = bh < 0 ? 0 : (bh > K ? K : bh);
    const int un_end = bin_start[bl];   // unchecked neg: [0, un_end)
    const int cn_end = bin_start[bh];   // checked  neg: [un_end, cn_end)

    const float cutp = ti + 0.1f;
    int pl = (int)floorf((cutp - 1e-4f) * (float)K);
    int ph = (int)floorf((cutp + 1e-4f) * (float)K) + 1;
    pl = pl < 0 ? 0 : (pl > K ? K : pl);
    ph = ph < 0 ? 0 : (ph > K ? K : ph);
    const int cp_beg = bin_start[pl];   // checked  pos: [cp_beg, up_beg)
    const int up_beg = bin_start[ph];   // unchecked pos: [up_beg, B)

    uint32_t Hn = 0, Jn = 0xFFFFFFFFu;
    bool fn = false;
    scan_main<KN.a, KN.b>(sorted_idx, 0, un_end, lane, base + KN.b, Hn, Jn);
    scan_bnd<KN.a, KN.b, true>(sorted_t, sorted_idx, un_end, cn_end, lane, ti,
                               base + KN.b, Hn, Jn, fn);
    const bool valid_n = (un_end > 0) || __any(fn);

    uint32_t Hp = 0, Jp = 0xFFFFFFFFu;
    bool fp2 = false;
    scan_main<KP.a, KP.b>(sorted_idx, up_beg, B, lane, base + KP.b, Hp, Jp);
    scan_bnd<KP.a, KP.b, false>(sorted_t, sorted_idx, cp_beg, up_beg, lane, ti,
                                base + KP.b, Hp, Jp, fp2);
    const bool valid_p = (up_beg < B) || __any(fp2);

    // In-wave (h, j) max-reduction with first-index tie-break.
    for (int off = 32; off > 0; off >>= 1) {
        const uint32_t ohn = __shfl_down(Hn, off, 64);
        const uint32_t ojn = __shfl_down(Jn, off, 64);
        if (ohn > Hn || (ohn == Hn && ojn < Jn)) { Hn = ohn; Jn = ojn; }
        const uint32_t ohp = __shfl_down(Hp, off, 64);
        const uint32_t ojp = __shfl_down(Jp, off, 64);
        if (ohp > Hp || (ohp == Hp && ojp < Jp)) { Hp = ohp; Jp = ojp; }
    }

    if (lane == 0) {
        float loss = 0.0f, valid = 0.0f;
        if (valid_n && valid_p) {
            const float per = 0.5f - (preds[Jp & 8191u] - preds[Jn & 8191u]);
            loss = per > 0.0f ? per : 0.0f;
            valid = 1.0f;
        }
        sl[wv] = loss; sv[wv] = valid;
    }
    __syncthreads();
    if (threadIdx.x == 0) {
        atomicAdd(loss_sum,  sl[0] + sl[1] + sl[2] + sl[3]);
        atomicAdd(valid_sum, sv[0] + sv[1] + sv[2] + sv[3]);
        __threadfence();
        const unsigned int old = atomicAdd(done, 1u);
        if (old == gridDim.x - 1u) {          // last block finalizes
            const float ls = atomicAdd(loss_sum, 0.0f);
            const float vs = atomicAdd(valid_sum, 0.0f);
            out[0] = vs > 0.0f ? ls / fmaxf(vs, 1.0f) : 0.0f;
        }
    }
}

extern "C" void kernel_launch(void* const* d_in, const int* in_sizes, int n_in,
                              void* d_out, int out_size, void* d_ws, size_t ws_size,
                              hipStream_t stream) {
    const float* preds   = (const float*)d_in[0];
    const float* targets = (const float*)d_in[1];

    // Layout identical to R4/R8 (proven): watermark ~57.4 KB. The 256 words
    // (512 u16 entries) after sorted_idx are the unroll-4 over-read slack.
    float* ws = (float*)d_ws;
    float*        sorted_t   = ws;                       // B floats
    uint16_t*     sorted_idx = (uint16_t*)(ws + B);      // B u16 + slack
    int*          bin_start  = (int*)(ws + B + B / 2 + 256); // K+1 ints
    float*        loss_sum   = ws + B + B / 2 + 2048;
    float*        valid_sum  = loss_sum + 1;
    unsigned int* done       = (unsigned int*)(loss_sum + 2);

    sort_kernel<<<1, 1024, 0, stream>>>(targets, sorted_t, sorted_idx, bin_start,
                                        loss_sum, valid_sum, done);
    rows_kernel<<<B / 4, 256, 0, stream>>>(preds, targets, sorted_t, sorted_idx,
                                           bin_start, loss_sum, valid_sum, done,
                                           (float*)d_out);
}